// Round 1
// 393.495 us; speedup vs baseline: 1.0792x; 1.0792x over previous
//
#include <hip/hip_runtime.h>

#define N_NODES 100000
#define IN_F 256
#define OUT_F 128
#define NB 782        // row buckets of 128 rows
#define CAP 2560      // per-bucket edge capacity (mean 2048, sigma 45 -> 11 sigma headroom)
#define QCAP 896      // per-quarter (32-row) capacity (mean 512, sigma 22.6 -> 17 sigma)
#define TILE 4096     // edges per scatter block

typedef __attribute__((ext_vector_type(8))) short v8s;
typedef __attribute__((ext_vector_type(4))) float v4f;

__device__ __forceinline__ unsigned short f2bf(float f) {
    unsigned int u = __float_as_uint(f);
    u += 0x7fffu + ((u >> 16) & 1u);
    return (unsigned short)(u >> 16);
}
__device__ __forceinline__ float bf2f(unsigned short s) {
    return __uint_as_float((unsigned int)s << 16);
}

// weight [K=256][F=128] fp32 -> bt bf16 [F=128][K=256]
__global__ void wt_kernel(const float* __restrict__ w, unsigned short* __restrict__ bt) {
    int idx = blockIdx.x * 256 + threadIdx.x;
    int k = idx >> 7;
    int n = idx & 127;
    bt[n * IN_F + k] = f2bf(w[idx]);
}

// thin bf16 GEMM with FUSED dropout on the A operand:
// support[N][128] (bf16) = dropout(x) @ bt^T
__global__ __launch_bounds__(256) void gemm_kernel(
    const float* __restrict__ x, const float* __restrict__ u,
    const unsigned short* __restrict__ bt, unsigned short* __restrict__ support) {
    __shared__ unsigned short As[128 * 72];
    __shared__ unsigned short Bs[128 * 72];

    const int tid  = threadIdx.x;
    const int lane = tid & 63;
    const int wv   = tid >> 6;
    const int wr   = wv >> 1, wc = wv & 1;
    const long long base = (long long)blockIdx.x * 128;

    v4f acc[4][4] = {};

    for (int k0 = 0; k0 < IN_F; k0 += 64) {
        if (k0) __syncthreads();
        {   // stage A: read fp32 input + drop_u, apply dropout, cast to bf16
            const int row = tid >> 1;
            const int kh  = (tid & 1) * 32;
            long long g = base + row;
            unsigned short* dst = &As[row * 72 + kh];
            if (g < N_NODES) {
                const float* xs = x + g * IN_F + k0 + kh;
                const float* us = u + g * IN_F + k0 + kh;
                #pragma unroll
                for (int i = 0; i < 8; ++i) {
                    float4 xi = *(const float4*)(xs + i * 4);
                    float4 du = *(const float4*)(us + i * 4);
                    ushort4 pk;
                    pk.x = f2bf(du.x > 0.2f ? xi.x * 1.25f : 0.0f);
                    pk.y = f2bf(du.y > 0.2f ? xi.y * 1.25f : 0.0f);
                    pk.z = f2bf(du.z > 0.2f ? xi.z * 1.25f : 0.0f);
                    pk.w = f2bf(du.w > 0.2f ? xi.w * 1.25f : 0.0f);
                    *(ushort4*)(dst + i * 4) = pk;
                }
            } else {
                #pragma unroll
                for (int i = 0; i < 4; ++i)
                    *(v8s*)(dst + i * 8) = (v8s){0,0,0,0,0,0,0,0};
            }
        }
        {   // stage B^T
            const int n  = tid >> 1;
            const int kh = (tid & 1) * 32;
            const unsigned short* src = bt + n * IN_F + k0 + kh;
            unsigned short* dst = &Bs[n * 72 + kh];
            #pragma unroll
            for (int i = 0; i < 4; ++i)
                *(v8s*)(dst + i * 8) = *(const v8s*)(src + i * 8);
        }
        __syncthreads();
        #pragma unroll
        for (int ks = 0; ks < 2; ++ks) {
            const int kb = ks * 32 + (lane >> 4) * 8;
            v8s af[4], bf[4];
            #pragma unroll
            for (int t = 0; t < 4; ++t)
                af[t] = *(const v8s*)&As[(wr * 64 + t * 16 + (lane & 15)) * 72 + kb];
            #pragma unroll
            for (int t = 0; t < 4; ++t)
                bf[t] = *(const v8s*)&Bs[(wc * 64 + t * 16 + (lane & 15)) * 72 + kb];
            #pragma unroll
            for (int tm = 0; tm < 4; ++tm)
                #pragma unroll
                for (int tn = 0; tn < 4; ++tn)
                    acc[tm][tn] = __builtin_amdgcn_mfma_f32_16x16x32_bf16(
                        af[tm], bf[tn], acc[tm][tn], 0, 0, 0);
        }
    }
    const int rq = lane >> 4;
    const int cl = lane & 15;
    #pragma unroll
    for (int tm = 0; tm < 4; ++tm) {
        #pragma unroll
        for (int r = 0; r < 4; ++r) {
            long long g = base + wr * 64 + tm * 16 + rq * 4 + r;
            if (g < N_NODES) {
                unsigned short* o = support + g * OUT_F + wc * 64 + cl;
                #pragma unroll
                for (int tn = 0; tn < 4; ++tn)
                    o[tn * 16] = f2bf(acc[tm][tn][r]);
            }
        }
    }
}

__global__ void init_kernel(int* __restrict__ cursor) {
    int i = blockIdx.x * 256 + threadIdx.x;
    if (i < NB) cursor[i * 16] = i * CAP;   // 64B-padded cursors
}

// coalesced bucket scatter: tile -> LDS hist -> scan -> reserve -> reorder -> run writes
__global__ __launch_bounds__(256) void scatter_kernel(
    const int* __restrict__ row, const int* __restrict__ col,
    const float* __restrict__ val, int* __restrict__ cursor,
    int2* __restrict__ cv, int E) {
    __shared__ int cnt[1024];
    __shared__ int loc[1024];
    __shared__ int delta[1024];
    __shared__ int tmp[256];
    __shared__ int gd[TILE];
    __shared__ int2 stage[TILE];
    __shared__ int total_s;
    const int tid = threadIdx.x;
    const int base_e = blockIdx.x * TILE;

    for (int i = tid; i < 1024; i += 256) cnt[i] = 0;
    __syncthreads();
    #pragma unroll
    for (int j = 0; j < TILE / 256; ++j) {
        int e = base_e + j * 256 + tid;
        if (e < E) atomicAdd(&cnt[row[e] >> 7], 1);
    }
    __syncthreads();
    int c0 = cnt[4*tid], c1 = cnt[4*tid+1], c2 = cnt[4*tid+2], c3 = cnt[4*tid+3];
    int s = c0 + c1 + c2 + c3;
    tmp[tid] = s;
    __syncthreads();
    #pragma unroll
    for (int d = 1; d < 256; d <<= 1) {
        int t = (tid >= d) ? tmp[tid - d] : 0;
        __syncthreads();
        tmp[tid] += t;
        __syncthreads();
    }
    int excl = tmp[tid] - s;
    loc[4*tid]   = excl;
    loc[4*tid+1] = excl + c0;
    loc[4*tid+2] = excl + c0 + c1;
    loc[4*tid+3] = excl + c0 + c1 + c2;
    if (tid == 255) total_s = tmp[255];
    __syncthreads();
    for (int i = tid; i < NB; i += 256) {
        int c = cnt[i];
        int gbase = 0;
        if (c > 0) gbase = atomicAdd(&cursor[i * 16], c);
        delta[i] = gbase - loc[i];
        cnt[i] = loc[i];
    }
    __syncthreads();
    #pragma unroll
    for (int j = 0; j < TILE / 256; ++j) {
        int e = base_e + j * 256 + tid;
        if (e < E) {
            int r = row[e];
            int b = r >> 7;
            int rank = atomicAdd(&cnt[b], 1);
            stage[rank] = make_int2(col[e] | ((r & 127) << 17), __float_as_int(val[e]));
            gd[rank] = delta[b] + rank;
        }
    }
    __syncthreads();
    int total = total_s;
    for (int i = tid; i < total; i += 256)
        cv[gd[i]] = stage[i];
}

// per-QUARTER-bucket (32 rows): LDS counting-sort by local row, then csr-style
// register-accumulate gather. 4 blocks per scatter bucket -> 3128 blocks, ~7.6KB LDS
// -> 8 blocks/CU (thread-limited) for latency hiding.
__global__ __launch_bounds__(256) void acc2_kernel(
    const int* __restrict__ cursor, const int2* __restrict__ cv,
    const unsigned short* __restrict__ support, float* __restrict__ out) {
    __shared__ int2 sorted[QCAP];    // 7168 B
    __shared__ int cnt_s[32];
    __shared__ int start_s[32];
    __shared__ int pos_s[32];
    const int tid = threadIdx.x;
    const int bq = blockIdx.x;
    const int b = bq >> 2;          // source 128-row bucket
    const int q = bq & 3;           // quarter: rows q*32 .. q*32+31
    const int e0 = b * CAP;
    const int nE = cursor[b * 16] - e0;

    if (tid < 32) cnt_s[tid] = 0;
    __syncthreads();
    // pass 1: histogram this quarter's local rows
    for (int i = tid; i < nE; i += 256) {
        int cx = cv[e0 + i].x;
        int lr = cx >> 17;
        if ((lr >> 5) == q) atomicAdd(&cnt_s[lr & 31], 1);
    }
    __syncthreads();
    // scan 32 bins with a single-wave shfl scan (no block barriers inside)
    if (tid < 32) {
        int v = cnt_s[tid];
        int sc = v;
        #pragma unroll
        for (int d = 1; d < 32; d <<= 1) {
            int t = __shfl_up(sc, d, 64);
            if (tid >= d) sc += t;
        }
        start_s[tid] = sc - v;
        pos_s[tid] = sc - v;
    }
    __syncthreads();
    // pass 2: reorder this quarter's edges into row-sorted LDS
    for (int i = tid; i < nE; i += 256) {
        int2 c = cv[e0 + i];
        int lr = c.x >> 17;
        if ((lr >> 5) == q) {
            int rank = atomicAdd(&pos_s[lr & 31], 1);
            sorted[rank] = c;
        }
    }
    __syncthreads();
    // gather: wave w owns rows w*8 .. w*8+7, register accumulate, one write/row
    const int lane = tid & 63, w = tid >> 6;
    const long long rowbase = (long long)b * 128 + q * 32;
    for (int rr = 0; rr < 8; ++rr) {
        int rl = w * 8 + rr;
        int e = start_s[rl];
        int end = e + cnt_s[rl];
        float a0 = 0.f, a1 = 0.f;
        for (; e < end; e += 4) {
            #pragma unroll
            for (int j = 0; j < 4; ++j) {
                int idx = e + j;
                int ids = min(idx, end - 1);
                int2 c = sorted[ids];
                float vv = (idx < end) ? __int_as_float(c.y) : 0.0f;
                int colv = c.x & 131071;
                unsigned int uu = *(const unsigned int*)(support + colv * OUT_F + lane * 2);
                a0 = fmaf(vv, bf2f((unsigned short)(uu & 0xffff)), a0);
                a1 = fmaf(vv, bf2f((unsigned short)(uu >> 16)), a1);
            }
        }
        long long g = rowbase + rl;
        if (g < N_NODES)
            *(float2*)(out + g * OUT_F + lane * 2) = make_float2(a0, a1);
    }
}

extern "C" void kernel_launch(void* const* d_in, const int* in_sizes, int n_in,
                              void* d_out, int out_size, void* d_ws, size_t ws_size,
                              hipStream_t stream) {
    const float* input   = (const float*)d_in[0];
    const float* weight  = (const float*)d_in[1];
    const int*   adj_row = (const int*)d_in[2];
    const int*   adj_col = (const int*)d_in[3];
    const float* adj_val = (const float*)d_in[4];
    const float* drop_u  = (const float*)d_in[5];
    float* out = (float*)d_out;
    const int E = in_sizes[2];

    // ws layout: bt 64K | cv int2 16M | support bf16 25.6M | cursor 50K
    char* p = (char*)d_ws;
    unsigned short* bt      = (unsigned short*)p;  p += 65536;
    int2*           cv      = (int2*)p;            p += (size_t)NB * CAP * sizeof(int2);
    unsigned short* support = (unsigned short*)p;  p += (size_t)N_NODES * OUT_F * 2;
    int*            cursor  = (int*)p;

    init_kernel<<<4, 256, 0, stream>>>(cursor);
    wt_kernel<<<128, 256, 0, stream>>>(weight, bt);
    gemm_kernel<<<(N_NODES + 127) / 128, 256, 0, stream>>>(input, drop_u, bt, support);
    scatter_kernel<<<(E + TILE - 1) / TILE, 256, 0, stream>>>(adj_row, adj_col, adj_val, cursor, cv, E);
    acc2_kernel<<<NB * 4, 256, 0, stream>>>(cursor, cv, support, out);
}

// Round 2
// 384.203 us; speedup vs baseline: 1.1053x; 1.0242x over previous
//
#include <hip/hip_runtime.h>

#define N_NODES 100000
#define IN_F 256
#define OUT_F 128
#define NB 782        // row buckets of 128 rows
#define CAP 2560      // per-bucket edge capacity (mean 2048, sigma 45 -> 11 sigma headroom)
#define QCAP 896      // per-quarter (32-row) capacity (mean 512, sigma 22.6 -> 17 sigma)
#define TILE 4096     // edges per scatter block
#define BPAD 42       // Bs leading-dim pad (odd*2 -> 16 distinct bank starts)

typedef __attribute__((ext_vector_type(8))) short v8s;
typedef __attribute__((ext_vector_type(4))) float v4f;

__device__ __forceinline__ unsigned short f2bf(float f) {
    unsigned int u = __float_as_uint(f);
    u += 0x7fffu + ((u >> 16) & 1u);
    return (unsigned short)(u >> 16);
}
__device__ __forceinline__ float bf2f(unsigned short s) {
    return __uint_as_float((unsigned int)s << 16);
}

// weight [K=256][F=128] fp32 -> bt bf16 [F=128][K=256]
__global__ void wt_kernel(const float* __restrict__ w, unsigned short* __restrict__ bt) {
    int idx = blockIdx.x * 256 + threadIdx.x;
    int k = idx >> 7;
    int n = idx & 127;
    bt[n * IN_F + k] = f2bf(w[idx]);
}

// thin bf16 GEMM, fused dropout, A direct-from-global (no A LDS):
// block = 64 rows x 128 cols, 4 waves of 16 rows each.
// B (64KB, L2-hot) double-buffered in LDS per 32-K step.
__global__ __launch_bounds__(256) void gemm_kernel(
    const float* __restrict__ x, const float* __restrict__ u,
    const unsigned short* __restrict__ bt, unsigned short* __restrict__ support) {
    __shared__ unsigned short Bs[2][128 * BPAD];

    const int tid  = threadIdx.x;
    const int lane = tid & 63;
    const int wv   = tid >> 6;
    const int cl   = lane & 15;
    const int kq   = lane >> 4;          // 0..3 -> k-chunk of 8
    const long long row = (long long)blockIdx.x * 64 + wv * 16 + cl;
    const bool rv = row < N_NODES;
    const long long rowc = rv ? row : (N_NODES - 1);
    const float* xs = x + rowc * IN_F + kq * 8;
    const float* us = u + rowc * IN_F + kq * 8;
    const float m = rv ? 1.25f : 0.0f;   // folds OOB-row zeroing into dropout scale

    // B staging ids: thread covers col=tid>>1, 16 k's
    const int scol = tid >> 1;
    const int skh  = (tid & 1) * 16;
    const unsigned short* bsrc = bt + scol * IN_F + skh;
    unsigned short* bdst0 = &Bs[0][scol * BPAD + skh];
    unsigned short* bdst1 = &Bs[1][scol * BPAD + skh];

    v4f acc[8] = {};

    // prologue: stage Bs[0] for k0=0
    *(v8s*)(bdst0)     = *(const v8s*)(bsrc);
    *(v8s*)(bdst0 + 8) = *(const v8s*)(bsrc + 8);
    __syncthreads();

    #pragma unroll
    for (int s = 0; s < 8; ++s) {
        const int k0 = s * 32;
        // A direct loads (issue early; 16 rows x 128B coalesced per wave)
        float4 x0 = *(const float4*)(xs + k0);
        float4 x1 = *(const float4*)(xs + k0 + 4);
        float4 u0 = *(const float4*)(us + k0);
        float4 u1 = *(const float4*)(us + k0 + 4);
        // stage next B tile into the other buffer
        if (s < 7) {
            const unsigned short* src = bsrc + (s + 1) * 32;
            unsigned short* dst = (s & 1) ? bdst0 : bdst1;
            *(v8s*)(dst)     = *(const v8s*)(src);
            *(v8s*)(dst + 8) = *(const v8s*)(src + 8);
        }
        // B fragments from current buffer
        const unsigned short* bb = (s & 1) ? &Bs[1][0] : &Bs[0][0];
        v8s bf[8];
        #pragma unroll
        for (int tn = 0; tn < 8; ++tn)
            bf[tn] = *(const v8s*)&bb[(tn * 16 + cl) * BPAD + kq * 8];
        // dropout + cast to bf16 fragment
        unsigned short t0 = f2bf(u0.x > 0.2f ? x0.x * m : 0.0f);
        unsigned short t1 = f2bf(u0.y > 0.2f ? x0.y * m : 0.0f);
        unsigned short t2 = f2bf(u0.z > 0.2f ? x0.z * m : 0.0f);
        unsigned short t3 = f2bf(u0.w > 0.2f ? x0.w * m : 0.0f);
        unsigned short t4 = f2bf(u1.x > 0.2f ? x1.x * m : 0.0f);
        unsigned short t5 = f2bf(u1.y > 0.2f ? x1.y * m : 0.0f);
        unsigned short t6 = f2bf(u1.z > 0.2f ? x1.z * m : 0.0f);
        unsigned short t7 = f2bf(u1.w > 0.2f ? x1.w * m : 0.0f);
        v8s af = {(short)t0, (short)t1, (short)t2, (short)t3,
                  (short)t4, (short)t5, (short)t6, (short)t7};
        #pragma unroll
        for (int tn = 0; tn < 8; ++tn)
            acc[tn] = __builtin_amdgcn_mfma_f32_16x16x32_bf16(af, bf[tn], acc[tn], 0, 0, 0);
        __syncthreads();
    }

    const int rq = lane >> 4;
    #pragma unroll
    for (int r = 0; r < 4; ++r) {
        long long g = (long long)blockIdx.x * 64 + wv * 16 + rq * 4 + r;
        if (g < N_NODES) {
            unsigned short* o = support + g * OUT_F + cl;
            #pragma unroll
            for (int tn = 0; tn < 8; ++tn)
                o[tn * 16] = f2bf(acc[tn][r]);
        }
    }
}

__global__ void init_kernel(int* __restrict__ cursor) {
    int i = blockIdx.x * 256 + threadIdx.x;
    if (i < NB) cursor[i * 16] = i * CAP;   // 64B-padded cursors
}

// coalesced bucket scatter: tile -> LDS hist -> scan -> reserve -> reorder -> run writes
__global__ __launch_bounds__(256) void scatter_kernel(
    const int* __restrict__ row, const int* __restrict__ col,
    const float* __restrict__ val, int* __restrict__ cursor,
    int2* __restrict__ cv, int E) {
    __shared__ int cnt[1024];
    __shared__ int loc[1024];
    __shared__ int delta[1024];
    __shared__ int tmp[256];
    __shared__ int gd[TILE];
    __shared__ int2 stage[TILE];
    __shared__ int total_s;
    const int tid = threadIdx.x;
    const int base_e = blockIdx.x * TILE;

    for (int i = tid; i < 1024; i += 256) cnt[i] = 0;
    __syncthreads();
    #pragma unroll
    for (int j = 0; j < TILE / 256; ++j) {
        int e = base_e + j * 256 + tid;
        if (e < E) atomicAdd(&cnt[row[e] >> 7], 1);
    }
    __syncthreads();
    int c0 = cnt[4*tid], c1 = cnt[4*tid+1], c2 = cnt[4*tid+2], c3 = cnt[4*tid+3];
    int s = c0 + c1 + c2 + c3;
    tmp[tid] = s;
    __syncthreads();
    #pragma unroll
    for (int d = 1; d < 256; d <<= 1) {
        int t = (tid >= d) ? tmp[tid - d] : 0;
        __syncthreads();
        tmp[tid] += t;
        __syncthreads();
    }
    int excl = tmp[tid] - s;
    loc[4*tid]   = excl;
    loc[4*tid+1] = excl + c0;
    loc[4*tid+2] = excl + c0 + c1;
    loc[4*tid+3] = excl + c0 + c1 + c2;
    if (tid == 255) total_s = tmp[255];
    __syncthreads();
    for (int i = tid; i < NB; i += 256) {
        int c = cnt[i];
        int gbase = 0;
        if (c > 0) gbase = atomicAdd(&cursor[i * 16], c);
        delta[i] = gbase - loc[i];
        cnt[i] = loc[i];
    }
    __syncthreads();
    #pragma unroll
    for (int j = 0; j < TILE / 256; ++j) {
        int e = base_e + j * 256 + tid;
        if (e < E) {
            int r = row[e];
            int b = r >> 7;
            int rank = atomicAdd(&cnt[b], 1);
            stage[rank] = make_int2(col[e] | ((r & 127) << 17), __float_as_int(val[e]));
            gd[rank] = delta[b] + rank;
        }
    }
    __syncthreads();
    int total = total_s;
    for (int i = tid; i < total; i += 256)
        cv[gd[i]] = stage[i];
}

// per-QUARTER-bucket (32 rows): single cv scan with register-held edges,
// LDS counting-sort by local row, then csr-style register-accumulate gather.
__global__ __launch_bounds__(256) void acc2_kernel(
    const int* __restrict__ cursor, const int2* __restrict__ cv,
    const unsigned short* __restrict__ support, float* __restrict__ out) {
    __shared__ int2 sorted[QCAP];    // 7168 B
    __shared__ int cnt_s[32];
    __shared__ int start_s[32];
    __shared__ int pos_s[32];
    const int tid = threadIdx.x;
    const int bq = blockIdx.x;
    const int b = bq >> 2;          // source 128-row bucket
    const int q = bq & 3;           // quarter: rows q*32 .. q*32+31
    const int e0 = b * CAP;
    const int nE = cursor[b * 16] - e0;

    if (tid < 32) cnt_s[tid] = 0;
    __syncthreads();
    // single pass: histogram + hold this quarter's edges in fixed register slots
    int2 ej[10];
    int  vj[10];                    // local row (0..31) if mine, else -1
    #pragma unroll
    for (int j = 0; j < 10; ++j) {  // 10*256 = 2560 = CAP, always in-bounds
        int i = j * 256 + tid;
        int2 c = cv[e0 + i];
        int lr = (c.x >> 17) & 127;
        int mine = (i < nE) && ((lr >> 5) == q);
        ej[j] = c;
        vj[j] = mine ? (lr & 31) : -1;
        if (mine) atomicAdd(&cnt_s[lr & 31], 1);
    }
    __syncthreads();
    // scan 32 bins with a single-wave shfl scan
    if (tid < 32) {
        int v = cnt_s[tid];
        int sc = v;
        #pragma unroll
        for (int d = 1; d < 32; d <<= 1) {
            int t = __shfl_up(sc, d, 64);
            if (tid >= d) sc += t;
        }
        start_s[tid] = sc - v;
        pos_s[tid] = sc - v;
    }
    __syncthreads();
    // place held edges into row-sorted LDS
    #pragma unroll
    for (int j = 0; j < 10; ++j) {
        if (vj[j] >= 0) {
            int rank = atomicAdd(&pos_s[vj[j]], 1);
            sorted[rank] = ej[j];
        }
    }
    __syncthreads();
    // gather: wave w owns rows w*8 .. w*8+7, register accumulate, one write/row
    const int lane = tid & 63, w = tid >> 6;
    const long long rowbase = (long long)b * 128 + q * 32;
    for (int rr = 0; rr < 8; ++rr) {
        int rl = w * 8 + rr;
        int e = start_s[rl];
        int end = e + cnt_s[rl];
        float a0 = 0.f, a1 = 0.f;
        for (; e < end; e += 4) {
            #pragma unroll
            for (int j = 0; j < 4; ++j) {
                int idx = e + j;
                int ids = min(idx, end - 1);
                int2 c = sorted[ids];
                float vv = (idx < end) ? __int_as_float(c.y) : 0.0f;
                int colv = c.x & 131071;
                unsigned int uu = *(const unsigned int*)(support + colv * OUT_F + lane * 2);
                a0 = fmaf(vv, bf2f((unsigned short)(uu & 0xffff)), a0);
                a1 = fmaf(vv, bf2f((unsigned short)(uu >> 16)), a1);
            }
        }
        long long g = rowbase + rl;
        if (g < N_NODES)
            *(float2*)(out + g * OUT_F + lane * 2) = make_float2(a0, a1);
    }
}

extern "C" void kernel_launch(void* const* d_in, const int* in_sizes, int n_in,
                              void* d_out, int out_size, void* d_ws, size_t ws_size,
                              hipStream_t stream) {
    const float* input   = (const float*)d_in[0];
    const float* weight  = (const float*)d_in[1];
    const int*   adj_row = (const int*)d_in[2];
    const int*   adj_col = (const int*)d_in[3];
    const float* adj_val = (const float*)d_in[4];
    const float* drop_u  = (const float*)d_in[5];
    float* out = (float*)d_out;
    const int E = in_sizes[2];

    // ws layout: bt 64K | cv int2 16M | support bf16 25.6M | cursor 50K
    char* p = (char*)d_ws;
    unsigned short* bt      = (unsigned short*)p;  p += 65536;
    int2*           cv      = (int2*)p;            p += (size_t)NB * CAP * sizeof(int2);
    unsigned short* support = (unsigned short*)p;  p += (size_t)N_NODES * OUT_F * 2;
    int*            cursor  = (int*)p;

    init_kernel<<<4, 256, 0, stream>>>(cursor);
    wt_kernel<<<128, 256, 0, stream>>>(weight, bt);
    gemm_kernel<<<(N_NODES + 63) / 64, 256, 0, stream>>>(input, drop_u, bt, support);
    scatter_kernel<<<(E + TILE - 1) / TILE, 256, 0, stream>>>(adj_row, adj_col, adj_val, cursor, cv, E);
    acc2_kernel<<<NB * 4, 256, 0, stream>>>(cursor, cv, support, out);
}